// Round 22
// baseline (352.519 us; speedup 1.0000x reference)
//
#include <hip/hip_runtime.h>
#include <hip/hip_bf16.h>
#include <stdint.h>

// PhaseAttention on MI355X, round 21:
//  - attn/packs: byte-identical to round-16..20 state.
//  - GEMMs: BK 64 -> 32. LDS halves to 64KB -> 2 blocks/CU (first time the
//    GEMM gets cross-block overlap; it has been 1 block/CU all session).
//    vmcnt re-derived: enter tile with 1 outstanding (=T.A1); front stages
//    {A0,B0,B1} (+3); VMC(3) retires T.A1; pB stages A1 (+1); VMC(1)
//    retires T+1.{A0,B0,B1}. Swizzle re-derived for 32-wide rows:
//    phys_granule = g ^ ((row>>1)&3)  (2 lanes/16B-slot = free).
//
//   A1[8192][2048] bf16 = [xr | xi] from z
//   Bp[8192][2048] bf16 = packed B^T rows; o-proj rows interleaved (o*2+part)
//   C1[8192][6144] bf16 = A1 x Bp[0:6144]
//   attention (banded, 320 keys/query) -> A2 (=A1 buffer)
//   out[8192][2048] f32 = A2 x Bp[6144:8192]  (flat, coalesced)

typedef __attribute__((ext_vector_type(8))) short bf16x8;
typedef __attribute__((ext_vector_type(8))) unsigned short u16x8;
typedef __attribute__((ext_vector_type(4))) float f32x4;

#define PA_SCALE 0.125f
#define UNR _Pragma("unroll")

__device__ __forceinline__ unsigned short f2bf(float f) {
  unsigned int u = __builtin_bit_cast(unsigned int, f);
  u += 0x7fffu + ((u >> 16) & 1u);
  return (unsigned short)(u >> 16);
}

#define GLD16(gp, lp)                                          \
  __builtin_amdgcn_global_load_lds(                            \
      (const __attribute__((address_space(1))) void*)(gp),     \
      (__attribute__((address_space(3))) void*)(lp), 16, 0, 0)

// ---------------- merged pack: A (blocks 0..4095) + B (4096..8191) ---------
__global__ __launch_bounds__(256) void pa_pack(
    const float* __restrict__ z,
    const float* __restrict__ Wq_r, const float* __restrict__ Wq_i,
    const float* __restrict__ Wk_r, const float* __restrict__ Wk_i,
    const float* __restrict__ Wv_r, const float* __restrict__ Wv_i,
    const float* __restrict__ Wo_r, const float* __restrict__ Wo_i,
    unsigned short* __restrict__ A1, unsigned short* __restrict__ Bp) {
  int bid = blockIdx.x, tid = threadIdx.x;
  if (bid < 4096) {
    int idx = (bid * 256 + tid) * 8;
    int m = idx >> 10, d = idx & 1023;
    const float2* zp = (const float2*)z + idx;
    u16x8 re, im;
    UNR for (int j = 0; j < 8; ++j) {
      float2 f = zp[j];
      re[j] = f2bf(f.x);
      im[j] = f2bf(f.y);
    }
    *(u16x8*)(A1 + (size_t)m * 2048 + d)        = re;
    *(u16x8*)(A1 + (size_t)m * 2048 + 1024 + d) = im;
  } else {
    int idx = ((bid - 4096) * 256 + tid) * 8;
    int n = idx >> 10, d = idx & 1023;
    int proj = n >> 11, part = (n >> 10) & 1, o = n & 1023;
    const float* Wr; const float* Wi;
    if (proj == 0)      { Wr = Wq_r; Wi = Wq_i; }
    else if (proj == 1) { Wr = Wk_r; Wi = Wk_i; }
    else if (proj == 2) { Wr = Wv_r; Wi = Wv_i; }
    else                { Wr = Wo_r; Wi = Wo_i; }
    const float* pr = Wr + (size_t)o * 1024 + d;
    const float* pi = Wi + (size_t)o * 1024 + d;
    u16x8 lo, hi;
    UNR for (int j = 0; j < 8; ++j) {
      float r = pr[j], im = pi[j];
      if (part == 0) { lo[j] = f2bf(r);  hi[j] = f2bf(-im); }
      else           { lo[j] = f2bf(im); hi[j] = f2bf(r);  }
    }
    size_t nn = (proj < 3) ? (size_t)n : (size_t)(6144 + o * 2 + part);
    *(u16x8*)(Bp + nn * 2048 + d)        = lo;
    *(u16x8*)(Bp + nn * 2048 + 1024 + d) = hi;
  }
}

// ---------------- 256x256 GEMM, BK=32, 2 blocks/CU -------------------------
// 512 thr = 8 waves (2M x 4N). LDS: 2 dbuf x {A0,A1,B0,B1} x 128x32 = 64KB.
// Swizzle: logical (row, colE) stored at colE ^ (((row>>1)&3)<<3).
#define BARR()                              \
  do {                                      \
    __builtin_amdgcn_s_barrier();           \
    __builtin_amdgcn_sched_barrier(0);      \
  } while (0)

#define READ_A(P, MH)                                                         \
  UNR for (int i = 0; i < 4; ++i)                                             \
    af[i] = *(const bf16x8*)&lds[P][MH][aoff + i * 512 + (koff ^ cxor)];

#define READ_B(P, NH, DST)                                                    \
  UNR for (int j = 0; j < 2; ++j)                                             \
    DST[j] = *(const bf16x8*)&lds[P][2 + (NH)][boff + j * 512 + (koff ^ cxor)];

#define MFMA_Q(MB, NB, BF)                                                    \
  UNR for (int i = 0; i < 4; ++i)                                             \
    UNR for (int j = 0; j < 2; ++j)                                           \
      acc[(MB) + i][(NB) + j] = __builtin_amdgcn_mfma_f32_16x16x32_bf16(      \
          af[i], BF[j], acc[(MB) + i][(NB) + j], 0, 0, 0);

#define VMC(N)                                                 \
  do {                                                         \
    asm volatile("s_waitcnt vmcnt(" #N ")" ::: "memory");      \
    __builtin_amdgcn_sched_barrier(0);                         \
  } while (0)

// Tile T (parity P): cluster A = quadrants (0,0)+(0,2); cluster B = (4,2)+(4,0).
// Invariant: tile entry outstanding = 1 (= T.A1).
//   pA front stages T+1.{A0,B0,B1} (+3 -> 4); VMC(3) retires T.A1;
//   pB stages T+1.A1 (+1 -> 4); VMC(1) retires T+1.{A0,B0,B1}.
#define TILE2(P, T)                                                           \
  {                                                                           \
    READ_A(P, 0);                                                             \
    READ_B(P, 0, b0);                                                         \
    __builtin_amdgcn_s_setprio(1);                                            \
    MFMA_Q(0, 0, b0);                                                         \
    __builtin_amdgcn_s_setprio(0);                                            \
    READ_B(P, 1, b1);                                                         \
    stageA(0, (T) + 1);                                                       \
    stageB(0, (T) + 1);                                                       \
    stageB(1, (T) + 1);                                                       \
    __builtin_amdgcn_s_setprio(1);                                            \
    MFMA_Q(0, 2, b1);                                                         \
    __builtin_amdgcn_s_setprio(0);                                            \
    VMC(3);                                                                   \
    BARR();                                                                   \
    READ_A(P, 1);                                                             \
    __builtin_amdgcn_s_setprio(1);                                            \
    MFMA_Q(4, 2, b1);                                                         \
    __builtin_amdgcn_s_setprio(0);                                            \
    stageA(1, (T) + 1);                                                       \
    __builtin_amdgcn_s_setprio(1);                                            \
    MFMA_Q(4, 0, b0);                                                         \
    __builtin_amdgcn_s_setprio(0);                                            \
    VMC(1);                                                                   \
    BARR();                                                                   \
  }

template <int EPI>
__global__ __launch_bounds__(512, 2) void pa_gemm8(
    const unsigned short* __restrict__ A,
    const unsigned short* __restrict__ B,
    void* __restrict__ Cout, int K, int N) {
  __shared__ unsigned short lds[2][4][128 * 32];   // 64 KiB -> 2 blocks/CU

  const int tid = threadIdx.x;
  const int lane = tid & 63, wid = tid >> 6;
  const int wm = wid >> 2, wn = wid & 3;
  const int lr = lane & 15, lh = lane >> 4;

  const int nwg = gridDim.x * gridDim.y;
  const int wg = blockIdx.y * gridDim.x + blockIdx.x;
  const int cpx = nwg >> 3;
  const int swz = (wg & 7) * cpx + (wg >> 3);
  const int bx = swz % gridDim.x, by = swz / gridDim.x;
  const int tm0 = by * 256, tn0 = bx * 256;

  const int NT = K >> 5;

  // staging: 512 chunks of 16B; chunk = tid; row = tid>>2, sg = tid&3
  const int srow = tid >> 2;         // uses all 512 threads -> per-wave rows
  const int ssg  = tid & 3;
  const int scolS = (ssg ^ ((srow >> 1) & 3)) * 8;   // inverse-swizzled source

  auto stageA = [&](int half, int ts) {
    int t = ts < NT ? ts : ts - NT;    // ghost tiles wrap (never consumed)
    const unsigned short* g0 = A + (size_t)(tm0 + half * 128 + (srow & 127)) * K +
                               t * 32 + scolS;
    unsigned short* l0 = &lds[ts & 1][half][0] + tid * 8;
    GLD16(g0, l0);
  };
  auto stageB = [&](int half, int ts) {
    int t = ts < NT ? ts : ts - NT;
    const unsigned short* g0 = B + (size_t)(tn0 + half * 128 + (srow & 127)) * K +
                               t * 32 + scolS;
    unsigned short* l0 = &lds[ts & 1][2 + half][0] + tid * 8;
    GLD16(g0, l0);
  };

  const int aoff = (wm * 64 + lr) * 32;
  const int boff = (wn * 32 + lr) * 32;
  const int koff = lh * 8;
  const int cxor = ((lr >> 1) & 3) * 8;   // read swizzle (row bases are x16)

  f32x4 acc[8][4];
  f32x4 zero4 = {0.f, 0.f, 0.f, 0.f};
  UNR for (int i = 0; i < 8; ++i)
    UNR for (int j = 0; j < 4; ++j) acc[i][j] = zero4;

  bf16x8 af[4], b0[2], b1[2];

  // prologue: stage tile 0 (A0,B0,B1,A1 = 4 loads); retire first 3
  stageA(0, 0); stageB(0, 0); stageB(1, 0); stageA(1, 0);
  asm volatile("s_waitcnt vmcnt(1)" ::: "memory");
  __builtin_amdgcn_sched_barrier(0);
  __builtin_amdgcn_s_barrier();
  __builtin_amdgcn_sched_barrier(0);

  for (int t = 0; t < NT; t += 2) {
    TILE2(0, t);
    TILE2(1, t + 1);
  }

  // epilogue
  UNR for (int mh = 0; mh < 2; ++mh)
    UNR for (int i = 0; i < 4; ++i)
      UNR for (int nh = 0; nh < 2; ++nh)
        UNR for (int j = 0; j < 2; ++j)
          UNR for (int r = 0; r < 4; ++r) {
            int row = tm0 + mh * 128 + wm * 64 + i * 16 + lh * 4 + r;
            int col = tn0 + nh * 128 + wn * 32 + j * 16 + lr;
            float v = acc[mh * 4 + i][nh * 2 + j][r];
            if (EPI == 0) {
              ((unsigned short*)Cout)[(size_t)row * N + col] = f2bf(v);
            } else {
              ((float*)Cout)[(size_t)row * N + col] = v;
            }
          }
}

// ---------------- banded attention (round-16 proven, byte-identical) -------
__global__ __launch_bounds__(512, 4) void pa_attn(const unsigned short* __restrict__ C1,
                                                  unsigned short* __restrict__ A2) {
  __shared__ unsigned short Ks[2][64][72];    // [re/im][key][hd]       18 KB
  __shared__ unsigned short Vts[2][64][72];   // [re/im][d][phys_key]   18 KB
  __shared__ unsigned short Ps[8][16][72];    // per-wave P stripe      18 KB

  int bid = blockIdx.x;
  int half = bid & 1, nc = (bid >> 1) & 15, h = (bid >> 5) & 15, b = bid >> 9;
  int tid = threadIdx.x;
  int l = tid & 63, wv = tid >> 6;
  int lr = l & 15, lh = l >> 4;

  const int C1LD = 6144;
  const int rowB = b * 4096;
  const int colQr = h * 64,        colQi = 1024 + h * 64;
  const int colKr = 2048 + h * 64, colKi = 3072 + h * 64;
  const int colVr = 4096 + h * 64, colVi = 5120 + h * 64;
  const int q0 = half * 128;
  const int qw = q0 + wv * 16;

  const int srow = (tid >> 3) & 63;
  const int ssg  = tid & 7;
  const int spk  = (srow & 7) | ((((srow >> 3) ^ ssg) & 7) << 3);

  bf16x8 qfr[2], qfi[2];
  {
    const unsigned short* pr = C1 + (size_t)(rowB + nc * 256 + qw + lr) * C1LD + colQr;
    const unsigned short* pi = C1 + (size_t)(rowB + nc * 256 + qw + lr) * C1LD + colQi;
    qfr[0] = *(const bf16x8*)(pr + lh * 8);
    qfr[1] = *(const bf16x8*)(pr + 32 + lh * 8);
    qfi[0] = *(const bf16x8*)(pi + lh * 8);
    qfi[1] = *(const bf16x8*)(pi + 32 + lh * 8);
  }

  const int dhi = lr >> 3;
  int voff[2][4];
  UNR for (int kk = 0; kk < 2; ++kk)
    UNR for (int fc = 0; fc < 4; ++fc)
      voff[kk][fc] = (((kk * 4 + lh) ^ ((fc * 2 + dhi) & 7)) << 3);

  f32x4 zero4 = {0.f, 0.f, 0.f, 0.f};
  float sm[4] = {0.f, 0.f, 0.f, 0.f};
  f32x4 oac[2][4];
#pragma unroll
  for (int p = 0; p < 2; ++p)
#pragma unroll
    for (int f = 0; f < 4; ++f) oac[p][f] = zero4;

  bf16x8 kr, ki, vr_, vi_;
  {
    int kj = q0 + srow;
    int tok = (nc - 1) * 256 + kj; if (tok < 0) tok = 0;
    const unsigned short* rp = C1 + (size_t)(rowB + tok) * C1LD + ssg * 8;
    kr  = *(const bf16x8*)(rp + colKr);
    ki  = *(const bf16x8*)(rp + colKi);
    vr_ = *(const bf16x8*)(rp + colVr);
    vi_ = *(const bf16x8*)(rp + colVi);
  }

#pragma unroll
  for (int c = 0; c < 6; ++c) {
    __syncthreads();
    *(bf16x8*)&Ks[0][srow][ssg * 8] = kr;
    *(bf16x8*)&Ks[1][srow][ssg * 8] = ki;
#pragma unroll
    for (int j = 0; j < 8; ++j) {
      Vts[0][ssg * 8 + j][spk] = (unsigned short)vr_[j];
      Vts[1][ssg * 8 + j][spk] = (unsigned short)vi_[j];
    }
    __syncthreads();

    if (c < 5) {
      int kj = q0 + (c + 1) * 64 + srow;
      int tok = (nc - 1) * 256 + kj; if (tok < 0) tok = 0;
      const unsigned short* rp = C1 + (size_t)(rowB + tok) * C1LD + ssg * 8;
      kr  = *(const bf16x8*)(rp + colKr);
      ki  = *(const bf16x8*)(rp + colKi);
      vr_ = *(const bf16x8*)(rp + colVr);
      vi_ = *(const bf16x8*)(rp + colVi);
    }

    bool active = (wv < 4) ? (c < 5) : (c >= 1);
    if (active) {
      f32x4 sl[4];
#pragma unroll
      for (int f = 0; f < 4; ++f) sl[f] = zero4;
      __builtin_amdgcn_s_setprio(1);
#pragma unroll
      for (int kk = 0; kk < 2; ++kk)
#pragma unroll
        for (int f = 0; f < 4; ++f) {
          bf16x8 br = *(const bf16x8*)&Ks[0][f * 16 + lr][kk * 32 + lh * 8];
          bf16x8 bi = *(const bf16x8*)&Ks[1][f * 16 + lr][kk * 32 + lh * 8];
          sl[f] = __builtin_amdgcn_mfma_f32_16x16x32_bf16(qfr[kk], br, sl[f], 0, 0, 0);
          sl[f] = __builtin_amdgcn_mfma_f32_16x16x32_bf16(qfi[kk], bi, sl[f], 0, 0, 0);
        }
      __builtin_amdgcn_s_setprio(0);

#pragma unroll
      for (int f = 0; f < 4; ++f)
#pragma unroll
        for (int r = 0; r < 4; ++r) {
          int qi_ = qw + lh * 4 + r;
          int kj  = q0 + c * 64 + f * 16 + lr;
          bool valid = (kj > qi_) && (kj <= qi_ + 256) && (nc > 0 || kj >= 256);
          float p = valid ? __expf(sl[f][r] * PA_SCALE) : 0.f;
          sm[r] += p;
          Ps[wv][lh * 4 + r][f * 16 + lr] = f2bf(p);
        }

      bf16x8 pa0 = *(const bf16x8*)&Ps[wv][lr][lh * 8];
      bf16x8 pa1 = *(const bf16x8*)&Ps[wv][lr][32 + lh * 8];
      __builtin_amdgcn_s_setprio(1);
#pragma unroll
      for (int kk = 0; kk < 2; ++kk) {
        bf16x8 pak = kk ? pa1 : pa0;
#pragma unroll
        for (int fc = 0; fc < 4; ++fc) {
          const unsigned short* vrp = &Vts[0][fc * 16 + lr][voff[kk][fc]];
          bf16x8 vv0 = *(const bf16x8*)vrp;
          bf16x8 vv1 = *(const bf16x8*)(vrp + 4608);
          oac[0][fc] = __builtin_amdgcn_mfma_f32_16x16x32_bf16(pak, vv0, oac[0][fc], 0, 0, 0);
          oac[1][fc] = __builtin_amdgcn_mfma_f32_16x16x32_bf16(pak, vv1, oac[1][fc], 0, 0, 0);
        }
      }
      __builtin_amdgcn_s_setprio(0);
    }
  }

#pragma unroll
  for (int r = 0; r < 4; ++r)
#pragma unroll
    for (int d = 1; d < 16; d <<= 1) sm[r] += __shfl_xor(sm[r], d);
  float inv[4];
#pragma unroll
  for (int r = 0; r < 4; ++r) inv[r] = 1.0f / sm[r];

#pragma unroll
  for (int fc = 0; fc < 4; ++fc)
#pragma unroll
    for (int r = 0; r < 4; ++r) {
      int m  = rowB + nc * 256 + qw + lh * 4 + r;
      int hd = fc * 16 + lr;
      A2[(size_t)m * 2048 + h * 64 + hd]        = f2bf(oac[0][fc][r] * inv[r]);
      A2[(size_t)m * 2048 + 1024 + h * 64 + hd] = f2bf(oac[1][fc][r] * inv[r]);
    }
}

// ---------------------------------------------------------------------------
extern "C" void kernel_launch(void* const* d_in, const int* in_sizes, int n_in,
                              void* d_out, int out_size, void* d_ws, size_t ws_size,
                              hipStream_t stream) {
  const float* z = (const float*)d_in[0];
  unsigned short* A1 = (unsigned short*)d_ws;                          // 32 MB
  unsigned short* Bp = (unsigned short*)((char*)d_ws + 33554432ull);   // 32 MB
  unsigned short* C1 = (unsigned short*)((char*)d_ws + 67108864ull);   // 96 MB
  float* out = (float*)d_out;

  pa_pack<<<8192, 256, 0, stream>>>(
      z,
      (const float*)d_in[1], (const float*)d_in[2],
      (const float*)d_in[3], (const float*)d_in[4],
      (const float*)d_in[5], (const float*)d_in[6],
      (const float*)d_in[7], (const float*)d_in[8], A1, Bp);
  // QKV projection: [8192x2048] x [2048x6144] -> C1 bf16
  pa_gemm8<0><<<dim3(24, 32), 512, 0, stream>>>(A1, Bp, C1, 2048, 6144);
  // banded attention -> A2 (reuses A1 buffer)
  pa_attn<<<1024, 512, 0, stream>>>(C1, A1);
  // output projection: [8192x2048] x [2048x2048] -> out f32 flat (coalesced)
  pa_gemm8<1><<<dim3(8, 32), 512, 0, stream>>>(A1, Bp + (size_t)6144 * 2048, out,
                                               2048, 2048);
}

// Round 23
// 330.710 us; speedup vs baseline: 1.0659x; 1.0659x over previous
//
#include <hip/hip_runtime.h>
#include <hip/hip_bf16.h>
#include <stdint.h>

// PhaseAttention on MI355X, round 22 (FINAL = round-20 proven best, 331.3us):
//  - r21's BK=32 reverted: occupancy was register-bound (92+128 acc = 220
//    VGPR/wave -> 2 waves/SIMD -> 1 block/CU regardless of LDS), so halved
//    BK only doubled barriers (G1 176.5 -> 195.5).
//  - GEMMs: 256x256 2-phase BK=64, 2 barriers/tile, counted vmcnt (6/2),
//    stage issues interleaved between MFMA groups, T2 swizzle, XCD swizzle.
//  - attn: fused single-pass no-max softmax + V granule swizzle + T14
//    async-stage split; 2 blocks/CU.
//  - packs merged; G2 epilogue coalesced via permuted Bp o-rows.
//
//   A1[8192][2048] bf16 = [xr | xi] from z
//   Bp[8192][2048] bf16 = packed B^T rows; o-proj rows interleaved (o*2+part)
//   C1[8192][6144] bf16 = A1 x Bp[0:6144]
//   attention (banded, 320 keys/query) -> A2 (=A1 buffer)
//   out[8192][2048] f32 = A2 x Bp[6144:8192]  (flat, coalesced)

typedef __attribute__((ext_vector_type(8))) short bf16x8;
typedef __attribute__((ext_vector_type(8))) unsigned short u16x8;
typedef __attribute__((ext_vector_type(4))) float f32x4;

#define PA_SCALE 0.125f
#define UNR _Pragma("unroll")

__device__ __forceinline__ unsigned short f2bf(float f) {
  unsigned int u = __builtin_bit_cast(unsigned int, f);
  u += 0x7fffu + ((u >> 16) & 1u);
  return (unsigned short)(u >> 16);
}

#define GLD16(gp, lp)                                          \
  __builtin_amdgcn_global_load_lds(                            \
      (const __attribute__((address_space(1))) void*)(gp),     \
      (__attribute__((address_space(3))) void*)(lp), 16, 0, 0)

// ---------------- merged pack: A (blocks 0..4095) + B (4096..8191) ---------
__global__ __launch_bounds__(256) void pa_pack(
    const float* __restrict__ z,
    const float* __restrict__ Wq_r, const float* __restrict__ Wq_i,
    const float* __restrict__ Wk_r, const float* __restrict__ Wk_i,
    const float* __restrict__ Wv_r, const float* __restrict__ Wv_i,
    const float* __restrict__ Wo_r, const float* __restrict__ Wo_i,
    unsigned short* __restrict__ A1, unsigned short* __restrict__ Bp) {
  int bid = blockIdx.x, tid = threadIdx.x;
  if (bid < 4096) {
    int idx = (bid * 256 + tid) * 8;
    int m = idx >> 10, d = idx & 1023;
    const float2* zp = (const float2*)z + idx;
    u16x8 re, im;
    UNR for (int j = 0; j < 8; ++j) {
      float2 f = zp[j];
      re[j] = f2bf(f.x);
      im[j] = f2bf(f.y);
    }
    *(u16x8*)(A1 + (size_t)m * 2048 + d)        = re;
    *(u16x8*)(A1 + (size_t)m * 2048 + 1024 + d) = im;
  } else {
    int idx = ((bid - 4096) * 256 + tid) * 8;
    int n = idx >> 10, d = idx & 1023;
    int proj = n >> 11, part = (n >> 10) & 1, o = n & 1023;
    const float* Wr; const float* Wi;
    if (proj == 0)      { Wr = Wq_r; Wi = Wq_i; }
    else if (proj == 1) { Wr = Wk_r; Wi = Wk_i; }
    else if (proj == 2) { Wr = Wv_r; Wi = Wv_i; }
    else                { Wr = Wo_r; Wi = Wo_i; }
    const float* pr = Wr + (size_t)o * 1024 + d;
    const float* pi = Wi + (size_t)o * 1024 + d;
    u16x8 lo, hi;
    UNR for (int j = 0; j < 8; ++j) {
      float r = pr[j], im = pi[j];
      if (part == 0) { lo[j] = f2bf(r);  hi[j] = f2bf(-im); }
      else           { lo[j] = f2bf(im); hi[j] = f2bf(r);  }
    }
    size_t nn = (proj < 3) ? (size_t)n : (size_t)(6144 + o * 2 + part);
    *(u16x8*)(Bp + nn * 2048 + d)        = lo;
    *(u16x8*)(Bp + nn * 2048 + 1024 + d) = hi;
  }
}

// ---------------- 256x256 2-phase GEMM, interleaved staging ----------------
// 512 thr = 8 waves (2M x 4N). BK=64. LDS: 2 dbuf x {A0,A1,B0,B1} x 128x64.
// T2 swizzle: logical (row, colE) stored at colE ^ ((row&7)*8).
#define BARR()                              \
  do {                                      \
    __builtin_amdgcn_s_barrier();           \
    __builtin_amdgcn_sched_barrier(0);      \
  } while (0)

#define READ_A(P, MH)                                                         \
  UNR for (int i = 0; i < 4; ++i)                                             \
    UNR for (int ks = 0; ks < 2; ++ks)                                        \
      af[i][ks] = *(const bf16x8*)&lds[P][MH][aoff + i * 1024 +               \
                                              ((ks * 32 + koff) ^ cxor)];

#define READ_B(P, NH, DST)                                                    \
  UNR for (int j = 0; j < 2; ++j)                                             \
    UNR for (int ks = 0; ks < 2; ++ks)                                        \
      DST[j][ks] = *(const bf16x8*)&lds[P][2 + (NH)][boff + j * 1024 +        \
                                                     ((ks * 32 + koff) ^ cxor)];

#define MFMA_Q(MB, NB, BF)                                                    \
  UNR for (int ks = 0; ks < 2; ++ks)                                          \
    UNR for (int i = 0; i < 4; ++i)                                           \
      UNR for (int j = 0; j < 2; ++j)                                         \
        acc[(MB) + i][(NB) + j] = __builtin_amdgcn_mfma_f32_16x16x32_bf16(    \
            af[i][ks], BF[j][ks], acc[(MB) + i][(NB) + j], 0, 0, 0);

#define VMC(N)                                                 \
  do {                                                         \
    asm volatile("s_waitcnt vmcnt(" #N ")" ::: "memory");      \
    __builtin_amdgcn_sched_barrier(0);                         \
  } while (0)

// Tile T (parity P): cluster A = quadrants (0,0)+(0,2); cluster B = (4,2)+(4,0).
// pA stages T+1.{A0,B0,B1} BETWEEN its two MFMA groups; pB stages T+1.{A1}
// between its two groups. Invariant: tile entry outstanding = 2 (= T.A1);
// VMC(6) retires T.A1; VMC(2) retires T+1.{A0,B0,B1}.
#define TILE2(P, T)                                                           \
  {                                                                           \
    READ_A(P, 0);                                                             \
    READ_B(P, 0, b0);                                                         \
    READ_B(P, 1, b1);                                                         \
    __builtin_amdgcn_s_setprio(1);                                            \
    MFMA_Q(0, 0, b0);                                                         \
    __builtin_amdgcn_s_setprio(0);                                            \
    stageA(0, (T) + 1);                                                       \
    stageB(0, (T) + 1);                                                       \
    stageB(1, (T) + 1);                                                       \
    __builtin_amdgcn_s_setprio(1);                                            \
    MFMA_Q(0, 2, b1);                                                         \
    __builtin_amdgcn_s_setprio(0);                                            \
    VMC(6);                                                                   \
    BARR();                                                                   \
    READ_A(P, 1);                                                             \
    __builtin_amdgcn_s_setprio(1);                                            \
    MFMA_Q(4, 2, b1);                                                         \
    __builtin_amdgcn_s_setprio(0);                                            \
    stageA(1, (T) + 1);                                                       \
    __builtin_amdgcn_s_setprio(1);                                            \
    MFMA_Q(4, 0, b0);                                                         \
    __builtin_amdgcn_s_setprio(0);                                            \
    VMC(2);                                                                   \
    BARR();                                                                   \
  }

template <int EPI>
__global__ __launch_bounds__(512, 2) void pa_gemm8(
    const unsigned short* __restrict__ A,
    const unsigned short* __restrict__ B,
    void* __restrict__ Cout, int K, int N) {
  __shared__ unsigned short lds[2][4][128 * 64];   // 128 KiB

  const int tid = threadIdx.x;
  const int lane = tid & 63, wid = tid >> 6;
  const int wm = wid >> 2, wn = wid & 3;
  const int lr = lane & 15, lh = lane >> 4;

  const int nwg = gridDim.x * gridDim.y;
  const int wg = blockIdx.y * gridDim.x + blockIdx.x;
  const int cpx = nwg >> 3;
  const int swz = (wg & 7) * cpx + (wg >> 3);
  const int bx = swz % gridDim.x, by = swz / gridDim.x;
  const int tm0 = by * 256, tn0 = bx * 256;

  const int NT = K >> 6;

  const int srow = lane >> 3;
  const int scolS = ((lane & 7) ^ srow) * 8;

  auto stageA = [&](int half, int ts) {
    int t = ts < NT ? ts : ts - NT;    // ghost tiles wrap (never consumed)
    const unsigned short* g0 = A + (size_t)(tm0 + half * 128) * K + t * 64 + scolS;
    unsigned short* l0 = &lds[ts & 1][half][0];
    UNR for (int c = 0; c < 2; ++c) {
      int chunk = wid * 2 + c;
      GLD16(g0 + (size_t)(chunk * 8 + srow) * K, l0 + chunk * 512);
    }
  };
  auto stageB = [&](int half, int ts) {
    int t = ts < NT ? ts : ts - NT;
    const unsigned short* g0 = B + (size_t)(tn0 + half * 128) * K + t * 64 + scolS;
    unsigned short* l0 = &lds[ts & 1][2 + half][0];
    UNR for (int c = 0; c < 2; ++c) {
      int chunk = wid * 2 + c;
      GLD16(g0 + (size_t)(chunk * 8 + srow) * K, l0 + chunk * 512);
    }
  };

  const int aoff = (wm * 64 + lr) * 64;
  const int boff = (wn * 32 + lr) * 64;
  const int koff = lh * 8;
  const int cxor = (lr & 7) * 8;

  f32x4 acc[8][4];
  f32x4 zero4 = {0.f, 0.f, 0.f, 0.f};
  UNR for (int i = 0; i < 8; ++i)
    UNR for (int j = 0; j < 4; ++j) acc[i][j] = zero4;

  bf16x8 af[4][2], b0[2][2], b1[2][2];

  // prologue: stage tile 0 fully; one-time full drain
  stageA(0, 0); stageB(0, 0); stageB(1, 0); stageA(1, 0);
  asm volatile("s_waitcnt vmcnt(0)" ::: "memory");
  __builtin_amdgcn_sched_barrier(0);
  __builtin_amdgcn_s_barrier();
  __builtin_amdgcn_sched_barrier(0);

  for (int t = 0; t < NT; t += 2) {
    TILE2(0, t);
    TILE2(1, t + 1);
  }

  // epilogue
  UNR for (int mh = 0; mh < 2; ++mh)
    UNR for (int i = 0; i < 4; ++i)
      UNR for (int nh = 0; nh < 2; ++nh)
        UNR for (int j = 0; j < 2; ++j)
          UNR for (int r = 0; r < 4; ++r) {
            int row = tm0 + mh * 128 + wm * 64 + i * 16 + lh * 4 + r;
            int col = tn0 + nh * 128 + wn * 32 + j * 16 + lr;
            float v = acc[mh * 4 + i][nh * 2 + j][r];
            if (EPI == 0) {
              ((unsigned short*)Cout)[(size_t)row * N + col] = f2bf(v);
            } else {
              ((float*)Cout)[(size_t)row * N + col] = v;
            }
          }
}

// ---------------- banded attention (round-16 proven, byte-identical) -------
__global__ __launch_bounds__(512, 4) void pa_attn(const unsigned short* __restrict__ C1,
                                                  unsigned short* __restrict__ A2) {
  __shared__ unsigned short Ks[2][64][72];    // [re/im][key][hd]       18 KB
  __shared__ unsigned short Vts[2][64][72];   // [re/im][d][phys_key]   18 KB
  __shared__ unsigned short Ps[8][16][72];    // per-wave P stripe      18 KB

  int bid = blockIdx.x;
  int half = bid & 1, nc = (bid >> 1) & 15, h = (bid >> 5) & 15, b = bid >> 9;
  int tid = threadIdx.x;
  int l = tid & 63, wv = tid >> 6;
  int lr = l & 15, lh = l >> 4;

  const int C1LD = 6144;
  const int rowB = b * 4096;
  const int colQr = h * 64,        colQi = 1024 + h * 64;
  const int colKr = 2048 + h * 64, colKi = 3072 + h * 64;
  const int colVr = 4096 + h * 64, colVi = 5120 + h * 64;
  const int q0 = half * 128;
  const int qw = q0 + wv * 16;

  const int srow = (tid >> 3) & 63;
  const int ssg  = tid & 7;
  const int spk  = (srow & 7) | ((((srow >> 3) ^ ssg) & 7) << 3);

  bf16x8 qfr[2], qfi[2];
  {
    const unsigned short* pr = C1 + (size_t)(rowB + nc * 256 + qw + lr) * C1LD + colQr;
    const unsigned short* pi = C1 + (size_t)(rowB + nc * 256 + qw + lr) * C1LD + colQi;
    qfr[0] = *(const bf16x8*)(pr + lh * 8);
    qfr[1] = *(const bf16x8*)(pr + 32 + lh * 8);
    qfi[0] = *(const bf16x8*)(pi + lh * 8);
    qfi[1] = *(const bf16x8*)(pi + 32 + lh * 8);
  }

  const int dhi = lr >> 3;
  int voff[2][4];
  UNR for (int kk = 0; kk < 2; ++kk)
    UNR for (int fc = 0; fc < 4; ++fc)
      voff[kk][fc] = (((kk * 4 + lh) ^ ((fc * 2 + dhi) & 7)) << 3);

  f32x4 zero4 = {0.f, 0.f, 0.f, 0.f};
  float sm[4] = {0.f, 0.f, 0.f, 0.f};
  f32x4 oac[2][4];
#pragma unroll
  for (int p = 0; p < 2; ++p)
#pragma unroll
    for (int f = 0; f < 4; ++f) oac[p][f] = zero4;

  bf16x8 kr, ki, vr_, vi_;
  {
    int kj = q0 + srow;
    int tok = (nc - 1) * 256 + kj; if (tok < 0) tok = 0;
    const unsigned short* rp = C1 + (size_t)(rowB + tok) * C1LD + ssg * 8;
    kr  = *(const bf16x8*)(rp + colKr);
    ki  = *(const bf16x8*)(rp + colKi);
    vr_ = *(const bf16x8*)(rp + colVr);
    vi_ = *(const bf16x8*)(rp + colVi);
  }

#pragma unroll
  for (int c = 0; c < 6; ++c) {
    __syncthreads();
    *(bf16x8*)&Ks[0][srow][ssg * 8] = kr;
    *(bf16x8*)&Ks[1][srow][ssg * 8] = ki;
#pragma unroll
    for (int j = 0; j < 8; ++j) {
      Vts[0][ssg * 8 + j][spk] = (unsigned short)vr_[j];
      Vts[1][ssg * 8 + j][spk] = (unsigned short)vi_[j];
    }
    __syncthreads();

    if (c < 5) {
      int kj = q0 + (c + 1) * 64 + srow;
      int tok = (nc - 1) * 256 + kj; if (tok < 0) tok = 0;
      const unsigned short* rp = C1 + (size_t)(rowB + tok) * C1LD + ssg * 8;
      kr  = *(const bf16x8*)(rp + colKr);
      ki  = *(const bf16x8*)(rp + colKi);
      vr_ = *(const bf16x8*)(rp + colVr);
      vi_ = *(const bf16x8*)(rp + colVi);
    }

    bool active = (wv < 4) ? (c < 5) : (c >= 1);
    if (active) {
      f32x4 sl[4];
#pragma unroll
      for (int f = 0; f < 4; ++f) sl[f] = zero4;
      __builtin_amdgcn_s_setprio(1);
#pragma unroll
      for (int kk = 0; kk < 2; ++kk)
#pragma unroll
        for (int f = 0; f < 4; ++f) {
          bf16x8 br = *(const bf16x8*)&Ks[0][f * 16 + lr][kk * 32 + lh * 8];
          bf16x8 bi = *(const bf16x8*)&Ks[1][f * 16 + lr][kk * 32 + lh * 8];
          sl[f] = __builtin_amdgcn_mfma_f32_16x16x32_bf16(qfr[kk], br, sl[f], 0, 0, 0);
          sl[f] = __builtin_amdgcn_mfma_f32_16x16x32_bf16(qfi[kk], bi, sl[f], 0, 0, 0);
        }
      __builtin_amdgcn_s_setprio(0);

#pragma unroll
      for (int f = 0; f < 4; ++f)
#pragma unroll
        for (int r = 0; r < 4; ++r) {
          int qi_ = qw + lh * 4 + r;
          int kj  = q0 + c * 64 + f * 16 + lr;
          bool valid = (kj > qi_) && (kj <= qi_ + 256) && (nc > 0 || kj >= 256);
          float p = valid ? __expf(sl[f][r] * PA_SCALE) : 0.f;
          sm[r] += p;
          Ps[wv][lh * 4 + r][f * 16 + lr] = f2bf(p);
        }

      bf16x8 pa0 = *(const bf16x8*)&Ps[wv][lr][lh * 8];
      bf16x8 pa1 = *(const bf16x8*)&Ps[wv][lr][32 + lh * 8];
      __builtin_amdgcn_s_setprio(1);
#pragma unroll
      for (int kk = 0; kk < 2; ++kk) {
        bf16x8 pak = kk ? pa1 : pa0;
#pragma unroll
        for (int fc = 0; fc < 4; ++fc) {
          const unsigned short* vrp = &Vts[0][fc * 16 + lr][voff[kk][fc]];
          bf16x8 vv0 = *(const bf16x8*)vrp;
          bf16x8 vv1 = *(const bf16x8*)(vrp + 4608);
          oac[0][fc] = __builtin_amdgcn_mfma_f32_16x16x32_bf16(pak, vv0, oac[0][fc], 0, 0, 0);
          oac[1][fc] = __builtin_amdgcn_mfma_f32_16x16x32_bf16(pak, vv1, oac[1][fc], 0, 0, 0);
        }
      }
      __builtin_amdgcn_s_setprio(0);
    }
  }

#pragma unroll
  for (int r = 0; r < 4; ++r)
#pragma unroll
    for (int d = 1; d < 16; d <<= 1) sm[r] += __shfl_xor(sm[r], d);
  float inv[4];
#pragma unroll
  for (int r = 0; r < 4; ++r) inv[r] = 1.0f / sm[r];

#pragma unroll
  for (int fc = 0; fc < 4; ++fc)
#pragma unroll
    for (int r = 0; r < 4; ++r) {
      int m  = rowB + nc * 256 + qw + lh * 4 + r;
      int hd = fc * 16 + lr;
      A2[(size_t)m * 2048 + h * 64 + hd]        = f2bf(oac[0][fc][r] * inv[r]);
      A2[(size_t)m * 2048 + 1024 + h * 64 + hd] = f2bf(oac[1][fc][r] * inv[r]);
    }
}

// ---------------------------------------------------------------------------
extern "C" void kernel_launch(void* const* d_in, const int* in_sizes, int n_in,
                              void* d_out, int out_size, void* d_ws, size_t ws_size,
                              hipStream_t stream) {
  const float* z = (const float*)d_in[0];
  unsigned short* A1 = (unsigned short*)d_ws;                          // 32 MB
  unsigned short* Bp = (unsigned short*)((char*)d_ws + 33554432ull);   // 32 MB
  unsigned short* C1 = (unsigned short*)((char*)d_ws + 67108864ull);   // 96 MB
  float* out = (float*)d_out;

  pa_pack<<<8192, 256, 0, stream>>>(
      z,
      (const float*)d_in[1], (const float*)d_in[2],
      (const float*)d_in[3], (const float*)d_in[4],
      (const float*)d_in[5], (const float*)d_in[6],
      (const float*)d_in[7], (const float*)d_in[8], A1, Bp);
  // QKV projection: [8192x2048] x [2048x6144] -> C1 bf16
  pa_gemm8<0><<<dim3(24, 32), 512, 0, stream>>>(A1, Bp, C1, 2048, 6144);
  // banded attention -> A2 (reuses A1 buffer)
  pa_attn<<<1024, 512, 0, stream>>>(C1, A1);
  // output projection: [8192x2048] x [2048x2048] -> out f32 flat (coalesced)
  pa_gemm8<1><<<dim3(8, 32), 512, 0, stream>>>(A1, Bp + (size_t)6144 * 2048, out,
                                               2048, 2048);
}